// Round 20
// baseline (236.523 us; speedup 1.0000x reference)
//
#include <hip/hip_runtime.h>
#include <cstdint>
#include <cstddef>

constexpr int N_NODES  = 20000;
constexpr int N_PAD    = 20224;   // 158*128
constexpr int N_EDGES  = 160000;
constexpr int N_GRAPHS = 16;
constexpr int SEQ_L    = 2048;
constexpr int F_IN     = 1024;
constexpr int D_OUT    = 128;
constexpr int N_DESC   = 80;
constexpr int K_PAD    = 104;
constexpr int N_CCH    = 16;
constexpr int ELL_CAP  = 64;
constexpr int S_SLICES = 32;
constexpr int ROWB     = N_PAD / 128;        // 158
constexpr int NWG_GEMM = 2 * ROWB * 8;       // 2528, divisible by 8
constexpr float SLOPE  = 0.01f;

// prep kernel (fill_ell + convT only)
constexpr int PR_FILL_END  = 2 * 625;                 // 1250
constexpr int PR_CONVT_END = PR_FILL_END + 2 * 1024;  // +2048

typedef short bf16x8 __attribute__((ext_vector_type(8)));
typedef float f32x4  __attribute__((ext_vector_type(4)));
typedef float f32x2  __attribute__((ext_vector_type(2)));
typedef int   i32x4v __attribute__((ext_vector_type(4)));
typedef int   i32x8v __attribute__((ext_vector_type(8)));

__device__ __forceinline__ float leaky(float x) { return x > 0.f ? x : SLOPE * x; }
__device__ __forceinline__ ushort f2bf(float f) {
  uint32_t u = __float_as_uint(f);
  uint32_t r = (u + 0x7FFFu + ((u >> 16) & 1u)) >> 16;
  return (ushort)r;
}
__device__ __forceinline__ float bf2f(ushort u) { return __uint_as_float(((uint32_t)u) << 16); }

// ---- fp8 e4m3fn manual converters (exponent-remap, RNE) ----
__device__ __forceinline__ unsigned char f2fp8(float f) {
  f = fminf(fmaxf(f, -448.f), 448.f);
  uint32_t u = __float_as_uint(f * 0x1.0p-120f);
  uint32_t s = (u >> 24) & 0x80u;
  uint32_t m = u & 0x7FFFFFFFu;
  m = m + 0x7FFFFu + ((m >> 20) & 1u);
  return (unsigned char)(s | (m >> 20));
}
__device__ __forceinline__ float fp82f(uint32_t b) {
  uint32_t bits = ((b & 0x80u) << 24) | ((b & 0x7Fu) << 20);
  return __uint_as_float(bits) * 0x1.0p+120f;
}

#if defined(__has_builtin)
#if __has_builtin(__builtin_amdgcn_cvt_pk_f32_fp8)
#define HAS_CVT_PK_FP8 1
#endif
#if __has_builtin(__builtin_amdgcn_cvt_pk_fp8_f32)
#define HAS_CVT_PK_FP8_ENC 1
#endif
#endif

// decode 4 packed fp8 (one u32) -> 4 floats
__device__ __forceinline__ void dec4(uint32_t wv, float* d) {
#ifdef HAS_CVT_PK_FP8
  f32x2 lo = __builtin_amdgcn_cvt_pk_f32_fp8((int)wv, false);
  f32x2 hi = __builtin_amdgcn_cvt_pk_f32_fp8((int)wv, true);
  d[0] = lo[0]; d[1] = lo[1]; d[2] = hi[0]; d[3] = hi[1];
#else
#pragma unroll
  for (int j = 0; j < 4; ++j) d[j] = fp82f((wv >> (8 * j)) & 0xFFu);
#endif
}

// encode 4 floats -> one u32 of packed fp8 (HW packed cvt when available)
__device__ __forceinline__ uint32_t pk4(float a, float b, float c, float d) {
#ifdef HAS_CVT_PK_FP8_ENC
  int r = 0;
  r = __builtin_amdgcn_cvt_pk_fp8_f32(a, b, r, false);
  r = __builtin_amdgcn_cvt_pk_fp8_f32(c, d, r, true);
  return (uint32_t)r;
#else
  return (uint32_t)f2fp8(a) | ((uint32_t)f2fp8(b) << 8) |
         ((uint32_t)f2fp8(c) << 16) | ((uint32_t)f2fp8(d) << 24);
#endif
}

__device__ __forceinline__ int lower_bound_i(const int* __restrict__ arr, int n, int val) {
  int lo = 0, hi = n;
  while (lo < hi) { int mid = (lo + hi) >> 1; if (arr[mid] < val) lo = mid + 1; else hi = mid; }
  return lo;
}

// ===== cast_x: x f32 -> fp8 (pad rows zero); COALESCED: one float4/lane/iter (16B stride) =====
__global__ __launch_bounds__(256) void cast_x(const float* __restrict__ x0,
                                              const float* __restrict__ x1,
                                              unsigned char* __restrict__ xf8) {
  const size_t total = (size_t)2 * N_PAD * (F_IN / 4);   // float4 chunks
  const size_t halfc = (size_t)N_PAD * (F_IN / 4);
  for (size_t idx = (size_t)blockIdx.x * 256 + threadIdx.x; idx < total;
       idx += (size_t)gridDim.x * 256) {
    const int z = idx >= halfc;
    const size_t c2 = idx - (size_t)z * halfc;
    const int row = (int)(c2 >> 8);          // 256 float4 per 1024-elem row
    uint32_t o = 0u;
    if (row < N_NODES) {
      float4 v = *((const float4*)(z ? x1 : x0) + c2);
      o = pk4(v.x, v.y, v.z, v.w);
    }
    *((uint32_t*)xf8 + idx) = o;
  }
}

// ============ prep: fill_ell | convT(fp8 x32) — small static LDS ============
__global__ __launch_bounds__(256) void prep_kernel(
    const int* __restrict__ e0, const int* __restrict__ e1,
    int* __restrict__ cnt, int* __restrict__ ell,
    const float* __restrict__ Wg0, const float* __restrict__ Wg1,
    unsigned char* __restrict__ wtf8) {
  __shared__ float tile[32][33];
  const int bid = blockIdx.x;
  const int t = threadIdx.x;

  if (bid < PR_FILL_END) {
    int z = bid >= 625;
    int i = (bid - z * 625) * 256 + t;
    const int* src = z ? e1 : e0;
    const int* dst = src + N_EDGES;
    int d = dst[i];
    int pos = atomicAdd(&cnt[z * N_NODES + d], 1);
    if (pos < ELL_CAP) ell[((size_t)z * N_NODES + d) * ELL_CAP + pos] = src[i];
  } else {
    int cb = bid - PR_FILL_END;
    int z = cb >= 1024;
    int cb2 = cb - z * 1024;
    const float* W = z ? Wg1 : Wg0;
    const int k0 = (cb2 & 31) * 32, n0 = (cb2 >> 5) * 32;
    const int tc = t & 31, tr = t >> 5;
#pragma unroll
    for (int q = 0; q < 4; ++q) {
      int r = tr + q * 8;
      tile[r][tc] = W[(size_t)(k0 + r) * F_IN + n0 + tc];
    }
    __syncthreads();
    unsigned char* Wz = wtf8 + (size_t)z * F_IN * F_IN;
#pragma unroll
    for (int q = 0; q < 4; ++q) {
      int r = tr + q * 8;
      Wz[(size_t)(n0 + r) * F_IN + k0 + tc] = f2fp8(tile[tc][r] * 32.0f);
    }
  }
}

// ============ conv1d(k=1) via MFMA — standalone, static 54 KB LDS, 1024 blocks ============
__global__ __launch_bounds__(256) void conv_mfma(
    const float* __restrict__ m0, const float* __restrict__ m1,
    const float* __restrict__ m2, const float* __restrict__ m3,
    const float* __restrict__ Wc0, const float* __restrict__ Wc1,
    const float* __restrict__ Wc2, const float* __restrict__ Wc3,
    float* __restrict__ pmax) {
  __shared__ ushort lA[128 * K_PAD];
  __shared__ ushort lB[128 * K_PAD];
  __shared__ float smax[4 * D_OUT];
  const int bid = blockIdx.x;
  const int t = threadIdx.x;
  const int ch = bid & 15, g = (bid >> 4) & 15, br = bid >> 8;
  const float* m = br == 0 ? m0 : br == 1 ? m1 : br == 2 ? m2 : m3;
  const float* W = br == 0 ? Wc0 : br == 1 ? Wc1 : br == 2 ? Wc2 : Wc3;
  const int lane = t & 63, w = t >> 6;

  for (int i = t; i < N_DESC * D_OUT; i += 256) {
    int k = i >> 7, col = i & 127;
    lB[col * K_PAD + k] = f2bf(W[i]);
  }
  for (int i = t; i < 128 * 16; i += 256) {
    int col = i >> 4, k = 80 + (i & 15);
    lB[col * K_PAD + k] = 0;
  }
  const float4* mg4 = (const float4*)(m + ((size_t)g * SEQ_L + (size_t)ch * 128) * N_DESC);
#pragma unroll
  for (int j = 0; j < 10; ++j) {
    int fi = t + j * 256;
    int row = fi / 20, off = fi - row * 20;
    float4 v = mg4[fi];
    ushort4 o;
    o.x = f2bf(v.x); o.y = f2bf(v.y); o.z = f2bf(v.z); o.w = f2bf(v.w);
    *(ushort4*)(lA + row * K_PAD + off * 4) = o;
  }
  if (t < 128) {
    ushort4 z4 = {0, 0, 0, 0};
    *(ushort4*)(lA + t * K_PAD + 80) = z4;
    *(ushort4*)(lA + t * K_PAD + 84) = z4;
    *(ushort4*)(lA + t * K_PAD + 88) = z4;
    *(ushort4*)(lA + t * K_PAD + 92) = z4;
  }
  __syncthreads();

  const int frow = lane & 15, fk = (lane >> 4) * 8;
  f32x4 acc[2][8] = {};
#pragma unroll
  for (int ks = 0; ks < 3; ++ks) {
    bf16x8 af[2], bfr[8];
#pragma unroll
    for (int mm = 0; mm < 2; ++mm)
      af[mm] = *(const bf16x8*)(lA + (w * 32 + mm * 16 + frow) * K_PAD + ks * 32 + fk);
#pragma unroll
    for (int n = 0; n < 8; ++n)
      bfr[n] = *(const bf16x8*)(lB + (n * 16 + frow) * K_PAD + ks * 32 + fk);
#pragma unroll
    for (int mm = 0; mm < 2; ++mm)
#pragma unroll
      for (int n = 0; n < 8; ++n)
        acc[mm][n] = __builtin_amdgcn_mfma_f32_16x16x32_bf16(af[mm], bfr[n], acc[mm][n], 0, 0, 0);
  }
  __syncthreads();

#pragma unroll
  for (int n = 0; n < 8; ++n) {
    float v = acc[0][n][0];
#pragma unroll
    for (int j = 1; j < 4; ++j) v = fmaxf(v, acc[0][n][j]);
#pragma unroll
    for (int j = 0; j < 4; ++j) v = fmaxf(v, acc[1][n][j]);
    v = fmaxf(v, __shfl_xor(v, 16, 64));
    v = fmaxf(v, __shfl_xor(v, 32, 64));
    if (lane < 16) smax[w * D_OUT + n * 16 + lane] = v;
  }
  __syncthreads();
  if (t < D_OUT) {
    float v = fmaxf(fmaxf(smax[t], smax[D_OUT + t]),
                    fmaxf(smax[2 * D_OUT + t], smax[3 * D_OUT + t]));
    pmax[(((size_t)br * N_GRAPHS + g) * N_CCH + ch) * D_OUT + t] = v;
  }
}

__device__ __forceinline__ i32x8v ld_frag8(const unsigned char* base, int s0, int s1) {
  i32x4v p0 = *(const i32x4v*)(base + (s0 << 4));
  i32x4v p1 = *(const i32x4v*)(base + (s1 << 4));
  i32x8v r;
  r[0] = p0[0]; r[1] = p0[1]; r[2] = p0[2]; r[3] = p0[3];
  r[4] = p1[0]; r[5] = p1[1]; r[6] = p1[2]; r[7] = p1[3];
  return r;
}

// ===== MX-fp8 MFMA GEMM: 128x128 tile, BK=128, mfma_scale 16x16x128, XOR-swizzled LDS =====
__global__ __launch_bounds__(256) void gemm_mx(const unsigned char* __restrict__ A,
                                               const unsigned char* __restrict__ Bt,
                                               const int* __restrict__ cnt,
                                               unsigned char* __restrict__ C) {
  const int bid = blockIdx.x;
  const int swz = (bid & 7) * (NWG_GEMM / 8) + (bid >> 3);
  const int br  = swz / (ROWB * 8);
  const int rem = swz - br * (ROWB * 8);
  const int rowb = rem >> 3, colb = rem & 7;

  const unsigned char* Az = A + (size_t)br * N_PAD * F_IN;
  const unsigned char* Bz = Bt + (size_t)br * F_IN * F_IN;
  unsigned char* Cz = C + (size_t)br * N_PAD * F_IN;
  const int* cz = cnt + br * N_NODES;

  __shared__ unsigned char lA[128 * 128];
  __shared__ unsigned char lB[128 * 128];
  const int t = threadIdx.x;
  const int lane = t & 63, w = t >> 6;
  const int wr = w >> 1, wc = w & 1;
  const int brow = rowb * 128, bcol = colb * 128;

  const int lr8 = lane >> 3;
  const int csw = ((lane & 7) ^ lr8) << 4;
  const unsigned char* gA[4]; const unsigned char* gB[4];
  int ldo[4];
#pragma unroll
  for (int g = 0; g < 4; ++g) {
    const int c = w * 4 + g;
    gA[g] = Az + (size_t)(brow + c * 8 + lr8) * F_IN + csw;
    gB[g] = Bz + (size_t)(bcol + c * 8 + lr8) * F_IN + csw;
    ldo[g] = c * 1024 + lane * 16;
  }

  f32x4 acc[4][4] = {};
  const int frow = lane & 15;
  const int kg = lane >> 4;
  const int xm = frow & 7;
  const int s0 = (2 * kg) ^ xm, s1 = (2 * kg + 1) ^ xm;

  for (int k0 = 0; k0 < F_IN; k0 += 128) {
#pragma unroll
    for (int g = 0; g < 4; ++g) {
      __builtin_amdgcn_global_load_lds((const __attribute__((address_space(1))) void*)(gA[g] + k0),
                                       (__attribute__((address_space(3))) void*)(lA + ldo[g]), 16, 0, 0);
      __builtin_amdgcn_global_load_lds((const __attribute__((address_space(1))) void*)(gB[g] + k0),
                                       (__attribute__((address_space(3))) void*)(lB + ldo[g]), 16, 0, 0);
    }
    __syncthreads();
    i32x8v af[4], bfv[4];
#pragma unroll
    for (int m = 0; m < 4; ++m)
      af[m] = ld_frag8(lA + (wr * 64 + m * 16 + frow) * 128, s0, s1);
#pragma unroll
    for (int n = 0; n < 4; ++n)
      bfv[n] = ld_frag8(lB + (wc * 64 + n * 16 + frow) * 128, s0, s1);
#pragma unroll
    for (int m = 0; m < 4; ++m)
#pragma unroll
      for (int n = 0; n < 4; ++n)
        acc[m][n] = __builtin_amdgcn_mfma_scale_f32_16x16x128_f8f6f4(
            af[m], bfv[n], acc[m][n], 0, 0,
            0, 0x7F7F7F7F,    // A scale = 2^0
            0, 0x7A7A7A7A);   // B scale = 2^-5
    __syncthreads();
  }

  float* ldv = (float*)lA;
  if (t < 128) {
    int row = brow + t;
    ldv[t] = (row < N_NODES) ? rsqrtf((float)(cz[row] + 1)) : 0.f;
  }
  __syncthreads();

#pragma unroll
  for (int m = 0; m < 4; ++m) {
    const int r0 = wr * 64 + m * 16 + (lane >> 4) * 4;
#pragma unroll
    for (int j = 0; j < 4; ++j) {
      const float dv = ldv[r0 + j];
      const int row = brow + r0 + j;
#pragma unroll
      for (int n = 0; n < 4; ++n) {
        const int col = bcol + wc * 64 + n * 16 + (lane & 15);
        Cz[(size_t)row * F_IN + col] = f2fp8(acc[m][n][j] * dv);
      }
    }
  }
}

// ===== GCN aggregate + mean-pool fused: uint4 row loads + HW packed fp8 decode =====
__global__ __launch_bounds__(256) void gcn_agg_pool(const unsigned char* __restrict__ hs,
                                                    const int* __restrict__ cnt,
                                                    const int* __restrict__ ell,
                                                    const int* __restrict__ bt0,
                                                    const int* __restrict__ bt1,
                                                    const float* __restrict__ b0,
                                                    const float* __restrict__ b1,
                                                    float* __restrict__ pool) {
  __shared__ float lp[4][1024];
  const int g = blockIdx.x;
  const int slice = blockIdx.y;
  const int z = blockIdx.z;
  const int sub = threadIdx.x >> 6;
  const int lane = threadIdx.x & 63;
  const int* batch = z ? bt1 : bt0;
  const unsigned char* hz = hs + (size_t)z * N_PAD * F_IN;
  const int* cz = cnt + z * N_NODES;
  const float* bias = z ? b1 : b0;

  int lo = lower_bound_i(batch, N_NODES, g);
  int hi = lower_bound_i(batch, N_NODES, g + 1);
  int per = (hi - lo + S_SLICES - 1) / S_SLICES;
  int a = lo + slice * per;
  int b = min(a + per, hi);
  if (a >= b) return;

  float bv[16];
#pragma unroll
  for (int k = 0; k < 4; ++k)
    *(float4*)(bv + 4 * k) = ((const float4*)bias)[lane * 4 + k];

  float pp[16] = {};
  for (int node = a + sub; node < b; node += 4) {
    const int deg = cz[node];
    const float din = rsqrtf((float)(deg + 1));
    uint4 hv = ((const uint4*)(hz + (size_t)node * F_IN))[lane];
    float acc[16];
    dec4(hv.x, acc); dec4(hv.y, acc + 4); dec4(hv.z, acc + 8); dec4(hv.w, acc + 12);
    const int* el = ell + ((size_t)z * N_NODES + node) * ELL_CAP;
    const int ne = min(deg, ELL_CAP);
    int e = 0;
    for (; e + 4 <= ne; e += 4) {
      int4 sx = *(const int4*)(el + e);
      uint4 v0 = ((const uint4*)(hz + (size_t)sx.x * F_IN))[lane];
      uint4 v1 = ((const uint4*)(hz + (size_t)sx.y * F_IN))[lane];
      uint4 v2 = ((const uint4*)(hz + (size_t)sx.z * F_IN))[lane];
      uint4 v3 = ((const uint4*)(hz + (size_t)sx.w * F_IN))[lane];
      float d0[16], d1[16], d2[16], d3[16];
      dec4(v0.x, d0); dec4(v0.y, d0 + 4); dec4(v0.z, d0 + 8); dec4(v0.w, d0 + 12);
      dec4(v1.x, d1); dec4(v1.y, d1 + 4); dec4(v1.z, d1 + 8); dec4(v1.w, d1 + 12);
      dec4(v2.x, d2); dec4(v2.y, d2 + 4); dec4(v2.z, d2 + 8); dec4(v2.w, d2 + 12);
      dec4(v3.x, d3); dec4(v3.y, d3 + 4); dec4(v3.z, d3 + 8); dec4(v3.w, d3 + 12);
#pragma unroll
      for (int j = 0; j < 16; ++j)
        acc[j] += (d0[j] + d1[j]) + (d2[j] + d3[j]);
    }
    for (; e < ne; ++e) {
      uint4 v0 = ((const uint4*)(hz + (size_t)el[e] * F_IN))[lane];
      float d0[16];
      dec4(v0.x, d0); dec4(v0.y, d0 + 4); dec4(v0.z, d0 + 8); dec4(v0.w, d0 + 12);
#pragma unroll
      for (int j = 0; j < 16; ++j) acc[j] += d0[j];
    }
#pragma unroll
    for (int j = 0; j < 16; ++j) pp[j] += leaky(din * acc[j] + bv[j]);
  }

#pragma unroll
  for (int k = 0; k < 4; ++k)
    *(float4*)(&lp[sub][lane * 16 + 4 * k]) = *(const float4*)(pp + 4 * k);
  __syncthreads();
  float* pg = pool + ((size_t)z * N_GRAPHS + g) * F_IN;
#pragma unroll
  for (int q = 0; q < 4; ++q) {
    int i = threadIdx.x + q * 256;
    float s = (lp[0][i] + lp[1][i]) + (lp[2][i] + lp[3][i]);
    atomicAdd(&pg[i], s);
  }
}

// ================= T1: conv_reduce | fc, fused =================
__global__ __launch_bounds__(256) void tail1(const float* __restrict__ pmax,
                                             const float* __restrict__ cb0, const float* __restrict__ cb1,
                                             const float* __restrict__ cb2, const float* __restrict__ cb3,
                                             const float* __restrict__ pool,
                                             const int* __restrict__ bt0, const int* __restrict__ bt1,
                                             const float* __restrict__ W0, const float* __restrict__ W1,
                                             const float* __restrict__ fb0, const float* __restrict__ fb1,
                                             float* __restrict__ combined) {
  __shared__ float p[2][F_IN];
  const int bid = blockIdx.x;
  const int t = threadIdx.x;
  if (bid < 32) {
    int i = bid * 256 + t;
    int br = i >> 11;
    int g = (i >> 7) & 15;
    int d = i & 127;
    const float* pm = pmax + ((size_t)(br * N_GRAPHS + g) * N_CCH) * D_OUT + d;
    float best = -3.4e38f;
#pragma unroll
    for (int ch = 0; ch < N_CCH; ++ch) best = fmaxf(best, pm[ch * D_OUT]);
    const float* bias = br == 0 ? cb0 : br == 1 ? cb1 : br == 2 ? cb2 : cb3;
    combined[g * (6 * D_OUT) + 2 * D_OUT + br * D_OUT + d] = leaky(best + bias[d]);
  } else {
    int idx = (bid - 32) * 2 + (t >> 7);
    int z = idx >> 4, g = idx & 15;
    int tt = t & 127, sub = t >> 7;
    const int* batch = z ? bt1 : bt0;
    const float* W = z ? W1 : W0;
    const float* bias = z ? fb1 : fb0;
    int lo = lower_bound_i(batch, N_NODES, g);
    int hi = lower_bound_i(batch, N_NODES, g + 1);
    float inv = 1.0f / (float)max(hi - lo, 1);
    const float* pg = pool + ((size_t)z * N_GRAPHS + g) * F_IN;
    for (int k = tt; k < F_IN; k += 128) p[sub][k] = pg[k] * inv;
    __syncthreads();
    float acc = 0.f;
    for (int k = 0; k < F_IN; ++k) acc = fmaf(p[sub][k], W[k * D_OUT + tt], acc);
    combined[g * (6 * D_OUT) + z * D_OUT + tt] = leaky(acc + bias[tt]);
  }
}

// ================= final linear =================
__global__ __launch_bounds__(256) void final_kernel(const float* __restrict__ combined,
                                                    const float* __restrict__ Wf,
                                                    const float* __restrict__ bf,
                                                    float* __restrict__ out) {
  const int g = blockIdx.x;
  const int t = threadIdx.x;
  float acc = 0.f;
  for (int k = t; k < 6 * D_OUT; k += 256) acc = fmaf(combined[g * 6 * D_OUT + k], Wf[k], acc);
  __shared__ float red[256];
  red[t] = acc;
  __syncthreads();
  for (int s = 128; s > 0; s >>= 1) {
    if (t < s) red[t] += red[t + s];
    __syncthreads();
  }
  if (t == 0) out[g] = red[0] + bf[0];
}

extern "C" void kernel_launch(void* const* d_in, const int* in_sizes, int n_in,
                              void* d_out, int out_size, void* d_ws, size_t ws_size,
                              hipStream_t stream) {
  const float* p1x  = (const float*)d_in[0];
  const int*   e1   = (const int*)d_in[1];
  const int*   bt1  = (const int*)d_in[2];
  const float* p2x  = (const float*)d_in[3];
  const int*   e2   = (const int*)d_in[4];
  const int*   bt2  = (const int*)d_in[5];
  const float* m1s  = (const float*)d_in[6];
  const float* m1f  = (const float*)d_in[7];
  const float* m2s  = (const float*)d_in[8];
  const float* m2f  = (const float*)d_in[9];
  const float* Wg1  = (const float*)d_in[10];
  const float* bg1  = (const float*)d_in[11];
  const float* Wfc1 = (const float*)d_in[12];
  const float* bfc1 = (const float*)d_in[13];
  const float* Wg2  = (const float*)d_in[14];
  const float* bg2  = (const float*)d_in[15];
  const float* Wfc2 = (const float*)d_in[16];
  const float* bfc2 = (const float*)d_in[17];
  const float* Wm1s = (const float*)d_in[18];
  const float* bm1s = (const float*)d_in[19];
  const float* Wm1f = (const float*)d_in[20];
  const float* bm1f = (const float*)d_in[21];
  const float* Wm2s = (const float*)d_in[22];
  const float* bm2s = (const float*)d_in[23];
  const float* Wm2f = (const float*)d_in[24];
  const float* bm2f = (const float*)d_in[25];
  const float* Wfin = (const float*)d_in[26];
  const float* bfin = (const float*)d_in[27];
  float* out = (float*)d_out;

  char* base = (char*)d_ws;
  size_t off = 0;
  auto alloc = [&](size_t bytes) -> void* {
    void* p = base + off;
    off = (off + bytes + 255) & ~(size_t)255;
    return p;
  };
  unsigned char* xf8  = (unsigned char*)alloc((size_t)2 * N_PAD * F_IN);
  unsigned char* wtf8 = (unsigned char*)alloc((size_t)2 * F_IN * F_IN);
  unsigned char* h    = (unsigned char*)alloc((size_t)2 * N_PAD * F_IN);
  size_t zoff0 = off;
  int*    cnt    = (int*)alloc((size_t)2 * N_NODES * 4);
  float*  pool   = (float*)alloc((size_t)2 * N_GRAPHS * F_IN * 4);
  size_t zbytes = off - zoff0;
  int*    ell    = (int*)alloc((size_t)2 * N_NODES * ELL_CAP * 4);
  float*  combined = (float*)alloc((size_t)N_GRAPHS * 6 * D_OUT * 4);
  float*  pmax   = (float*)alloc((size_t)4 * N_GRAPHS * N_CCH * D_OUT * 4);
  (void)ws_size; (void)in_sizes; (void)n_in; (void)out_size;

  hipMemsetAsync((char*)base + zoff0, 0, zbytes, stream);

  cast_x<<<2048, 256, 0, stream>>>(p1x, p2x, xf8);
  prep_kernel<<<PR_CONVT_END, 256, 0, stream>>>(e1, e2, cnt, ell, Wg1, Wg2, wtf8);
  conv_mfma<<<1024, 256, 0, stream>>>(m1s, m1f, m2s, m2f, Wm1s, Wm1f, Wm2s, Wm2f, pmax);

  gemm_mx<<<NWG_GEMM, 256, 0, stream>>>(xf8, wtf8, cnt, h);

  gcn_agg_pool<<<dim3(N_GRAPHS, S_SLICES, 2), 256, 0, stream>>>(h, cnt, ell, bt1, bt2, bg1, bg2, pool);

  tail1<<<48, 256, 0, stream>>>(pmax, bm1s, bm1f, bm2s, bm2f,
                                pool, bt1, bt2, Wfc1, Wfc2, bfc1, bfc2, combined);

  final_kernel<<<N_GRAPHS, 256, 0, stream>>>(combined, Wfin, bfin, out);
}

// Round 21
// 234.351 us; speedup vs baseline: 1.0093x; 1.0093x over previous
//
#include <hip/hip_runtime.h>
#include <cstdint>
#include <cstddef>

constexpr int N_NODES  = 20000;
constexpr int N_PAD    = 20224;   // 158*128
constexpr int N_EDGES  = 160000;
constexpr int N_GRAPHS = 16;
constexpr int SEQ_L    = 2048;
constexpr int F_IN     = 1024;
constexpr int D_OUT    = 128;
constexpr int N_DESC   = 80;
constexpr int K_PAD    = 104;
constexpr int N_CCH    = 16;
constexpr int ELL_CAP  = 64;
constexpr int S_SLICES = 32;
constexpr int ROWB     = N_PAD / 128;        // 158
constexpr int NWG_GEMM = 2 * ROWB * 8;       // 2528, divisible by 8
constexpr float SLOPE  = 0.01f;

// prep kernel (fill_ell + convT only)
constexpr int PR_FILL_END  = 2 * 625;                 // 1250
constexpr int PR_CONVT_END = PR_FILL_END + 2 * 1024;  // +2048

typedef short bf16x8 __attribute__((ext_vector_type(8)));
typedef float f32x4  __attribute__((ext_vector_type(4)));
typedef float f32x2  __attribute__((ext_vector_type(2)));
typedef int   i32x4v __attribute__((ext_vector_type(4)));
typedef int   i32x8v __attribute__((ext_vector_type(8)));

__device__ __forceinline__ float leaky(float x) { return x > 0.f ? x : SLOPE * x; }
__device__ __forceinline__ ushort f2bf(float f) {
  uint32_t u = __float_as_uint(f);
  uint32_t r = (u + 0x7FFFu + ((u >> 16) & 1u)) >> 16;
  return (ushort)r;
}
__device__ __forceinline__ float bf2f(ushort u) { return __uint_as_float(((uint32_t)u) << 16); }

// ---- fp8 e4m3fn manual converters (exponent-remap, RNE) ----
__device__ __forceinline__ unsigned char f2fp8(float f) {
  f = fminf(fmaxf(f, -448.f), 448.f);
  uint32_t u = __float_as_uint(f * 0x1.0p-120f);
  uint32_t s = (u >> 24) & 0x80u;
  uint32_t m = u & 0x7FFFFFFFu;
  m = m + 0x7FFFFu + ((m >> 20) & 1u);
  return (unsigned char)(s | (m >> 20));
}
__device__ __forceinline__ float fp82f(uint32_t b) {
  uint32_t bits = ((b & 0x80u) << 24) | ((b & 0x7Fu) << 20);
  return __uint_as_float(bits) * 0x1.0p+120f;
}

#if defined(__has_builtin)
#if __has_builtin(__builtin_amdgcn_cvt_pk_f32_fp8)
#define HAS_CVT_PK_FP8 1
#endif
#if __has_builtin(__builtin_amdgcn_cvt_pk_fp8_f32)
#define HAS_CVT_PK_FP8_ENC 1
#endif
#endif

// decode 4 packed fp8 (one u32) -> 4 floats
__device__ __forceinline__ void dec4(uint32_t wv, float* d) {
#ifdef HAS_CVT_PK_FP8
  f32x2 lo = __builtin_amdgcn_cvt_pk_f32_fp8((int)wv, false);
  f32x2 hi = __builtin_amdgcn_cvt_pk_f32_fp8((int)wv, true);
  d[0] = lo[0]; d[1] = lo[1]; d[2] = hi[0]; d[3] = hi[1];
#else
#pragma unroll
  for (int j = 0; j < 4; ++j) d[j] = fp82f((wv >> (8 * j)) & 0xFFu);
#endif
}

// encode 4 floats -> one u32 of packed fp8 (HW packed cvt when available)
__device__ __forceinline__ uint32_t pk4(float a, float b, float c, float d) {
#ifdef HAS_CVT_PK_FP8_ENC
  int r = 0;
  r = __builtin_amdgcn_cvt_pk_fp8_f32(a, b, r, false);
  r = __builtin_amdgcn_cvt_pk_fp8_f32(c, d, r, true);
  return (uint32_t)r;
#else
  return (uint32_t)f2fp8(a) | ((uint32_t)f2fp8(b) << 8) |
         ((uint32_t)f2fp8(c) << 16) | ((uint32_t)f2fp8(d) << 24);
#endif
}

__device__ __forceinline__ int lower_bound_i(const int* __restrict__ arr, int n, int val) {
  int lo = 0, hi = n;
  while (lo < hi) { int mid = (lo + hi) >> 1; if (arr[mid] < val) lo = mid + 1; else hi = mid; }
  return lo;
}

// ===== cast_x v3: block-strided, fully coalesced BOTH sides, 4 independent chains/iter =====
// chunk = one float4 (16B in, one packed u32 out). C divisible by 1024 -> no inner guard.
__global__ __launch_bounds__(256) void cast_x(const float* __restrict__ x0,
                                              const float* __restrict__ x1,
                                              unsigned char* __restrict__ xf8) {
  const size_t C = (size_t)2 * N_PAD * (F_IN / 4);      // 10,354,688 (divisible by 1024)
  const size_t halfc = (size_t)N_PAD * (F_IN / 4);
  uint32_t* outw = (uint32_t*)xf8;
  for (size_t b0 = (size_t)blockIdx.x * 1024; b0 < C; b0 += (size_t)gridDim.x * 1024) {
    float4 v[4];
    size_t idx[4];
#pragma unroll
    for (int q = 0; q < 4; ++q) {
      idx[q] = b0 + (size_t)q * 256 + threadIdx.x;
      const int z = idx[q] >= halfc;
      const size_t c2 = idx[q] - (size_t)z * halfc;
      const int row = (int)(c2 >> 8);                   // 256 float4 per row
      if (row < N_NODES) {
        v[q] = *((const float4*)(z ? x1 : x0) + c2);
      } else {
        v[q] = make_float4(0.f, 0.f, 0.f, 0.f);
      }
    }
#pragma unroll
    for (int q = 0; q < 4; ++q)
      outw[idx[q]] = pk4(v[q].x, v[q].y, v[q].z, v[q].w);
  }
}

// ============ prep: fill_ell | convT(fp8 x32) — small static LDS ============
__global__ __launch_bounds__(256) void prep_kernel(
    const int* __restrict__ e0, const int* __restrict__ e1,
    int* __restrict__ cnt, int* __restrict__ ell,
    const float* __restrict__ Wg0, const float* __restrict__ Wg1,
    unsigned char* __restrict__ wtf8) {
  __shared__ float tile[32][33];
  const int bid = blockIdx.x;
  const int t = threadIdx.x;

  if (bid < PR_FILL_END) {
    int z = bid >= 625;
    int i = (bid - z * 625) * 256 + t;
    const int* src = z ? e1 : e0;
    const int* dst = src + N_EDGES;
    int d = dst[i];
    int pos = atomicAdd(&cnt[z * N_NODES + d], 1);
    if (pos < ELL_CAP) ell[((size_t)z * N_NODES + d) * ELL_CAP + pos] = src[i];
  } else {
    int cb = bid - PR_FILL_END;
    int z = cb >= 1024;
    int cb2 = cb - z * 1024;
    const float* W = z ? Wg1 : Wg0;
    const int k0 = (cb2 & 31) * 32, n0 = (cb2 >> 5) * 32;
    const int tc = t & 31, tr = t >> 5;
#pragma unroll
    for (int q = 0; q < 4; ++q) {
      int r = tr + q * 8;
      tile[r][tc] = W[(size_t)(k0 + r) * F_IN + n0 + tc];
    }
    __syncthreads();
    unsigned char* Wz = wtf8 + (size_t)z * F_IN * F_IN;
#pragma unroll
    for (int q = 0; q < 4; ++q) {
      int r = tr + q * 8;
      Wz[(size_t)(n0 + r) * F_IN + k0 + tc] = f2fp8(tile[tc][r] * 32.0f);
    }
  }
}

// ============ conv1d(k=1) via MFMA — standalone, static 54 KB LDS, 1024 blocks ============
__global__ __launch_bounds__(256) void conv_mfma(
    const float* __restrict__ m0, const float* __restrict__ m1,
    const float* __restrict__ m2, const float* __restrict__ m3,
    const float* __restrict__ Wc0, const float* __restrict__ Wc1,
    const float* __restrict__ Wc2, const float* __restrict__ Wc3,
    float* __restrict__ pmax) {
  __shared__ ushort lA[128 * K_PAD];
  __shared__ ushort lB[128 * K_PAD];
  __shared__ float smax[4 * D_OUT];
  const int bid = blockIdx.x;
  const int t = threadIdx.x;
  const int ch = bid & 15, g = (bid >> 4) & 15, br = bid >> 8;
  const float* m = br == 0 ? m0 : br == 1 ? m1 : br == 2 ? m2 : m3;
  const float* W = br == 0 ? Wc0 : br == 1 ? Wc1 : br == 2 ? Wc2 : Wc3;
  const int lane = t & 63, w = t >> 6;

  for (int i = t; i < N_DESC * D_OUT; i += 256) {
    int k = i >> 7, col = i & 127;
    lB[col * K_PAD + k] = f2bf(W[i]);
  }
  for (int i = t; i < 128 * 16; i += 256) {
    int col = i >> 4, k = 80 + (i & 15);
    lB[col * K_PAD + k] = 0;
  }
  const float4* mg4 = (const float4*)(m + ((size_t)g * SEQ_L + (size_t)ch * 128) * N_DESC);
#pragma unroll
  for (int j = 0; j < 10; ++j) {
    int fi = t + j * 256;
    int row = fi / 20, off = fi - row * 20;
    float4 v = mg4[fi];
    ushort4 o;
    o.x = f2bf(v.x); o.y = f2bf(v.y); o.z = f2bf(v.z); o.w = f2bf(v.w);
    *(ushort4*)(lA + row * K_PAD + off * 4) = o;
  }
  if (t < 128) {
    ushort4 z4 = {0, 0, 0, 0};
    *(ushort4*)(lA + t * K_PAD + 80) = z4;
    *(ushort4*)(lA + t * K_PAD + 84) = z4;
    *(ushort4*)(lA + t * K_PAD + 88) = z4;
    *(ushort4*)(lA + t * K_PAD + 92) = z4;
  }
  __syncthreads();

  const int frow = lane & 15, fk = (lane >> 4) * 8;
  f32x4 acc[2][8] = {};
#pragma unroll
  for (int ks = 0; ks < 3; ++ks) {
    bf16x8 af[2], bfr[8];
#pragma unroll
    for (int mm = 0; mm < 2; ++mm)
      af[mm] = *(const bf16x8*)(lA + (w * 32 + mm * 16 + frow) * K_PAD + ks * 32 + fk);
#pragma unroll
    for (int n = 0; n < 8; ++n)
      bfr[n] = *(const bf16x8*)(lB + (n * 16 + frow) * K_PAD + ks * 32 + fk);
#pragma unroll
    for (int mm = 0; mm < 2; ++mm)
#pragma unroll
      for (int n = 0; n < 8; ++n)
        acc[mm][n] = __builtin_amdgcn_mfma_f32_16x16x32_bf16(af[mm], bfr[n], acc[mm][n], 0, 0, 0);
  }
  __syncthreads();

#pragma unroll
  for (int n = 0; n < 8; ++n) {
    float v = acc[0][n][0];
#pragma unroll
    for (int j = 1; j < 4; ++j) v = fmaxf(v, acc[0][n][j]);
#pragma unroll
    for (int j = 0; j < 4; ++j) v = fmaxf(v, acc[1][n][j]);
    v = fmaxf(v, __shfl_xor(v, 16, 64));
    v = fmaxf(v, __shfl_xor(v, 32, 64));
    if (lane < 16) smax[w * D_OUT + n * 16 + lane] = v;
  }
  __syncthreads();
  if (t < D_OUT) {
    float v = fmaxf(fmaxf(smax[t], smax[D_OUT + t]),
                    fmaxf(smax[2 * D_OUT + t], smax[3 * D_OUT + t]));
    pmax[(((size_t)br * N_GRAPHS + g) * N_CCH + ch) * D_OUT + t] = v;
  }
}

__device__ __forceinline__ i32x8v ld_frag8(const unsigned char* base, int s0, int s1) {
  i32x4v p0 = *(const i32x4v*)(base + (s0 << 4));
  i32x4v p1 = *(const i32x4v*)(base + (s1 << 4));
  i32x8v r;
  r[0] = p0[0]; r[1] = p0[1]; r[2] = p0[2]; r[3] = p0[3];
  r[4] = p1[0]; r[5] = p1[1]; r[6] = p1[2]; r[7] = p1[3];
  return r;
}

// ===== MX-fp8 MFMA GEMM: 128x128 tile, BK=128, mfma_scale 16x16x128, XOR-swizzled LDS =====
__global__ __launch_bounds__(256) void gemm_mx(const unsigned char* __restrict__ A,
                                               const unsigned char* __restrict__ Bt,
                                               const int* __restrict__ cnt,
                                               unsigned char* __restrict__ C) {
  const int bid = blockIdx.x;
  const int swz = (bid & 7) * (NWG_GEMM / 8) + (bid >> 3);
  const int br  = swz / (ROWB * 8);
  const int rem = swz - br * (ROWB * 8);
  const int rowb = rem >> 3, colb = rem & 7;

  const unsigned char* Az = A + (size_t)br * N_PAD * F_IN;
  const unsigned char* Bz = Bt + (size_t)br * F_IN * F_IN;
  unsigned char* Cz = C + (size_t)br * N_PAD * F_IN;
  const int* cz = cnt + br * N_NODES;

  __shared__ unsigned char lA[128 * 128];
  __shared__ unsigned char lB[128 * 128];
  const int t = threadIdx.x;
  const int lane = t & 63, w = t >> 6;
  const int wr = w >> 1, wc = w & 1;
  const int brow = rowb * 128, bcol = colb * 128;

  const int lr8 = lane >> 3;
  const int csw = ((lane & 7) ^ lr8) << 4;
  const unsigned char* gA[4]; const unsigned char* gB[4];
  int ldo[4];
#pragma unroll
  for (int g = 0; g < 4; ++g) {
    const int c = w * 4 + g;
    gA[g] = Az + (size_t)(brow + c * 8 + lr8) * F_IN + csw;
    gB[g] = Bz + (size_t)(bcol + c * 8 + lr8) * F_IN + csw;
    ldo[g] = c * 1024 + lane * 16;
  }

  f32x4 acc[4][4] = {};
  const int frow = lane & 15;
  const int kg = lane >> 4;
  const int xm = frow & 7;
  const int s0 = (2 * kg) ^ xm, s1 = (2 * kg + 1) ^ xm;

  for (int k0 = 0; k0 < F_IN; k0 += 128) {
#pragma unroll
    for (int g = 0; g < 4; ++g) {
      __builtin_amdgcn_global_load_lds((const __attribute__((address_space(1))) void*)(gA[g] + k0),
                                       (__attribute__((address_space(3))) void*)(lA + ldo[g]), 16, 0, 0);
      __builtin_amdgcn_global_load_lds((const __attribute__((address_space(1))) void*)(gB[g] + k0),
                                       (__attribute__((address_space(3))) void*)(lB + ldo[g]), 16, 0, 0);
    }
    __syncthreads();
    i32x8v af[4], bfv[4];
#pragma unroll
    for (int m = 0; m < 4; ++m)
      af[m] = ld_frag8(lA + (wr * 64 + m * 16 + frow) * 128, s0, s1);
#pragma unroll
    for (int n = 0; n < 4; ++n)
      bfv[n] = ld_frag8(lB + (wc * 64 + n * 16 + frow) * 128, s0, s1);
#pragma unroll
    for (int m = 0; m < 4; ++m)
#pragma unroll
      for (int n = 0; n < 4; ++n)
        acc[m][n] = __builtin_amdgcn_mfma_scale_f32_16x16x128_f8f6f4(
            af[m], bfv[n], acc[m][n], 0, 0,
            0, 0x7F7F7F7F,    // A scale = 2^0
            0, 0x7A7A7A7A);   // B scale = 2^-5
    __syncthreads();
  }

  float* ldv = (float*)lA;
  if (t < 128) {
    int row = brow + t;
    ldv[t] = (row < N_NODES) ? rsqrtf((float)(cz[row] + 1)) : 0.f;
  }
  __syncthreads();

#pragma unroll
  for (int m = 0; m < 4; ++m) {
    const int r0 = wr * 64 + m * 16 + (lane >> 4) * 4;
#pragma unroll
    for (int j = 0; j < 4; ++j) {
      const float dv = ldv[r0 + j];
      const int row = brow + r0 + j;
#pragma unroll
      for (int n = 0; n < 4; ++n) {
        const int col = bcol + wc * 64 + n * 16 + (lane & 15);
        Cz[(size_t)row * F_IN + col] = f2fp8(acc[m][n][j] * dv);
      }
    }
  }
}

// ===== GCN aggregate + mean-pool fused: uint4 row loads + HW packed fp8 decode =====
__global__ __launch_bounds__(256) void gcn_agg_pool(const unsigned char* __restrict__ hs,
                                                    const int* __restrict__ cnt,
                                                    const int* __restrict__ ell,
                                                    const int* __restrict__ bt0,
                                                    const int* __restrict__ bt1,
                                                    const float* __restrict__ b0,
                                                    const float* __restrict__ b1,
                                                    float* __restrict__ pool) {
  __shared__ float lp[4][1024];
  const int g = blockIdx.x;
  const int slice = blockIdx.y;
  const int z = blockIdx.z;
  const int sub = threadIdx.x >> 6;
  const int lane = threadIdx.x & 63;
  const int* batch = z ? bt1 : bt0;
  const unsigned char* hz = hs + (size_t)z * N_PAD * F_IN;
  const int* cz = cnt + z * N_NODES;
  const float* bias = z ? b1 : b0;

  int lo = lower_bound_i(batch, N_NODES, g);
  int hi = lower_bound_i(batch, N_NODES, g + 1);
  int per = (hi - lo + S_SLICES - 1) / S_SLICES;
  int a = lo + slice * per;
  int b = min(a + per, hi);
  if (a >= b) return;

  float bv[16];
#pragma unroll
  for (int k = 0; k < 4; ++k)
    *(float4*)(bv + 4 * k) = ((const float4*)bias)[lane * 4 + k];

  float pp[16] = {};
  for (int node = a + sub; node < b; node += 4) {
    const int deg = cz[node];
    const float din = rsqrtf((float)(deg + 1));
    uint4 hv = ((const uint4*)(hz + (size_t)node * F_IN))[lane];
    float acc[16];
    dec4(hv.x, acc); dec4(hv.y, acc + 4); dec4(hv.z, acc + 8); dec4(hv.w, acc + 12);
    const int* el = ell + ((size_t)z * N_NODES + node) * ELL_CAP;
    const int ne = min(deg, ELL_CAP);
    int e = 0;
    for (; e + 4 <= ne; e += 4) {
      int4 sx = *(const int4*)(el + e);
      uint4 v0 = ((const uint4*)(hz + (size_t)sx.x * F_IN))[lane];
      uint4 v1 = ((const uint4*)(hz + (size_t)sx.y * F_IN))[lane];
      uint4 v2 = ((const uint4*)(hz + (size_t)sx.z * F_IN))[lane];
      uint4 v3 = ((const uint4*)(hz + (size_t)sx.w * F_IN))[lane];
      float d0[16], d1[16], d2[16], d3[16];
      dec4(v0.x, d0); dec4(v0.y, d0 + 4); dec4(v0.z, d0 + 8); dec4(v0.w, d0 + 12);
      dec4(v1.x, d1); dec4(v1.y, d1 + 4); dec4(v1.z, d1 + 8); dec4(v1.w, d1 + 12);
      dec4(v2.x, d2); dec4(v2.y, d2 + 4); dec4(v2.z, d2 + 8); dec4(v2.w, d2 + 12);
      dec4(v3.x, d3); dec4(v3.y, d3 + 4); dec4(v3.z, d3 + 8); dec4(v3.w, d3 + 12);
#pragma unroll
      for (int j = 0; j < 16; ++j)
        acc[j] += (d0[j] + d1[j]) + (d2[j] + d3[j]);
    }
    for (; e < ne; ++e) {
      uint4 v0 = ((const uint4*)(hz + (size_t)el[e] * F_IN))[lane];
      float d0[16];
      dec4(v0.x, d0); dec4(v0.y, d0 + 4); dec4(v0.z, d0 + 8); dec4(v0.w, d0 + 12);
#pragma unroll
      for (int j = 0; j < 16; ++j) acc[j] += d0[j];
    }
#pragma unroll
    for (int j = 0; j < 16; ++j) pp[j] += leaky(din * acc[j] + bv[j]);
  }

#pragma unroll
  for (int k = 0; k < 4; ++k)
    *(float4*)(&lp[sub][lane * 16 + 4 * k]) = *(const float4*)(pp + 4 * k);
  __syncthreads();
  float* pg = pool + ((size_t)z * N_GRAPHS + g) * F_IN;
#pragma unroll
  for (int q = 0; q < 4; ++q) {
    int i = threadIdx.x + q * 256;
    float s = (lp[0][i] + lp[1][i]) + (lp[2][i] + lp[3][i]);
    atomicAdd(&pg[i], s);
  }
}

// ================= T1: conv_reduce | fc, fused =================
__global__ __launch_bounds__(256) void tail1(const float* __restrict__ pmax,
                                             const float* __restrict__ cb0, const float* __restrict__ cb1,
                                             const float* __restrict__ cb2, const float* __restrict__ cb3,
                                             const float* __restrict__ pool,
                                             const int* __restrict__ bt0, const int* __restrict__ bt1,
                                             const float* __restrict__ W0, const float* __restrict__ W1,
                                             const float* __restrict__ fb0, const float* __restrict__ fb1,
                                             float* __restrict__ combined) {
  __shared__ float p[2][F_IN];
  const int bid = blockIdx.x;
  const int t = threadIdx.x;
  if (bid < 32) {
    int i = bid * 256 + t;
    int br = i >> 11;
    int g = (i >> 7) & 15;
    int d = i & 127;
    const float* pm = pmax + ((size_t)(br * N_GRAPHS + g) * N_CCH) * D_OUT + d;
    float best = -3.4e38f;
#pragma unroll
    for (int ch = 0; ch < N_CCH; ++ch) best = fmaxf(best, pm[ch * D_OUT]);
    const float* bias = br == 0 ? cb0 : br == 1 ? cb1 : br == 2 ? cb2 : cb3;
    combined[g * (6 * D_OUT) + 2 * D_OUT + br * D_OUT + d] = leaky(best + bias[d]);
  } else {
    int idx = (bid - 32) * 2 + (t >> 7);
    int z = idx >> 4, g = idx & 15;
    int tt = t & 127, sub = t >> 7;
    const int* batch = z ? bt1 : bt0;
    const float* W = z ? W1 : W0;
    const float* bias = z ? fb1 : fb0;
    int lo = lower_bound_i(batch, N_NODES, g);
    int hi = lower_bound_i(batch, N_NODES, g + 1);
    float inv = 1.0f / (float)max(hi - lo, 1);
    const float* pg = pool + ((size_t)z * N_GRAPHS + g) * F_IN;
    for (int k = tt; k < F_IN; k += 128) p[sub][k] = pg[k] * inv;
    __syncthreads();
    float acc = 0.f;
    for (int k = 0; k < F_IN; ++k) acc = fmaf(p[sub][k], W[k * D_OUT + tt], acc);
    combined[g * (6 * D_OUT) + z * D_OUT + tt] = leaky(acc + bias[tt]);
  }
}

// ================= final linear =================
__global__ __launch_bounds__(256) void final_kernel(const float* __restrict__ combined,
                                                    const float* __restrict__ Wf,
                                                    const float* __restrict__ bf,
                                                    float* __restrict__ out) {
  const int g = blockIdx.x;
  const int t = threadIdx.x;
  float acc = 0.f;
  for (int k = t; k < 6 * D_OUT; k += 256) acc = fmaf(combined[g * 6 * D_OUT + k], Wf[k], acc);
  __shared__ float red[256];
  red[t] = acc;
  __syncthreads();
  for (int s = 128; s > 0; s >>= 1) {
    if (t < s) red[t] += red[t + s];
    __syncthreads();
  }
  if (t == 0) out[g] = red[0] + bf[0];
}

extern "C" void kernel_launch(void* const* d_in, const int* in_sizes, int n_in,
                              void* d_out, int out_size, void* d_ws, size_t ws_size,
                              hipStream_t stream) {
  const float* p1x  = (const float*)d_in[0];
  const int*   e1   = (const int*)d_in[1];
  const int*   bt1  = (const int*)d_in[2];
  const float* p2x  = (const float*)d_in[3];
  const int*   e2   = (const int*)d_in[4];
  const int*   bt2  = (const int*)d_in[5];
  const float* m1s  = (const float*)d_in[6];
  const float* m1f  = (const float*)d_in[7];
  const float* m2s  = (const float*)d_in[8];
  const float* m2f  = (const float*)d_in[9];
  const float* Wg1  = (const float*)d_in[10];
  const float* bg1  = (const float*)d_in[11];
  const float* Wfc1 = (const float*)d_in[12];
  const float* bfc1 = (const float*)d_in[13];
  const float* Wg2  = (const float*)d_in[14];
  const float* bg2  = (const float*)d_in[15];
  const float* Wfc2 = (const float*)d_in[16];
  const float* bfc2 = (const float*)d_in[17];
  const float* Wm1s = (const float*)d_in[18];
  const float* bm1s = (const float*)d_in[19];
  const float* Wm1f = (const float*)d_in[20];
  const float* bm1f = (const float*)d_in[21];
  const float* Wm2s = (const float*)d_in[22];
  const float* bm2s = (const float*)d_in[23];
  const float* Wm2f = (const float*)d_in[24];
  const float* bm2f = (const float*)d_in[25];
  const float* Wfin = (const float*)d_in[26];
  const float* bfin = (const float*)d_in[27];
  float* out = (float*)d_out;

  char* base = (char*)d_ws;
  size_t off = 0;
  auto alloc = [&](size_t bytes) -> void* {
    void* p = base + off;
    off = (off + bytes + 255) & ~(size_t)255;
    return p;
  };
  unsigned char* xf8  = (unsigned char*)alloc((size_t)2 * N_PAD * F_IN);
  unsigned char* wtf8 = (unsigned char*)alloc((size_t)2 * F_IN * F_IN);
  unsigned char* h    = (unsigned char*)alloc((size_t)2 * N_PAD * F_IN);
  size_t zoff0 = off;
  int*    cnt    = (int*)alloc((size_t)2 * N_NODES * 4);
  float*  pool   = (float*)alloc((size_t)2 * N_GRAPHS * F_IN * 4);
  size_t zbytes = off - zoff0;
  int*    ell    = (int*)alloc((size_t)2 * N_NODES * ELL_CAP * 4);
  float*  combined = (float*)alloc((size_t)N_GRAPHS * 6 * D_OUT * 4);
  float*  pmax   = (float*)alloc((size_t)4 * N_GRAPHS * N_CCH * D_OUT * 4);
  (void)ws_size; (void)in_sizes; (void)n_in; (void)out_size;

  hipMemsetAsync((char*)base + zoff0, 0, zbytes, stream);

  cast_x<<<2048, 256, 0, stream>>>(p1x, p2x, xf8);
  prep_kernel<<<PR_CONVT_END, 256, 0, stream>>>(e1, e2, cnt, ell, Wg1, Wg2, wtf8);
  conv_mfma<<<1024, 256, 0, stream>>>(m1s, m1f, m2s, m2f, Wm1s, Wm1f, Wm2s, Wm2f, pmax);

  gemm_mx<<<NWG_GEMM, 256, 0, stream>>>(xf8, wtf8, cnt, h);

  gcn_agg_pool<<<dim3(N_GRAPHS, S_SLICES, 2), 256, 0, stream>>>(h, cnt, ell, bt1, bt2, bg1, bg2, pool);

  tail1<<<48, 256, 0, stream>>>(pmax, bm1s, bm1f, bm2s, bm2f,
                                pool, bt1, bt2, Wfc1, Wfc2, bfc1, bfc2, combined);

  final_kernel<<<N_GRAPHS, 256, 0, stream>>>(combined, Wfin, bfin, out);
}

// Round 22
// 219.722 us; speedup vs baseline: 1.0765x; 1.0666x over previous
//
#include <hip/hip_runtime.h>
#include <cstdint>
#include <cstddef>

constexpr int N_NODES  = 20000;
constexpr int N_PAD    = 20224;   // 158*128
constexpr int N_EDGES  = 160000;
constexpr int N_GRAPHS = 16;
constexpr int SEQ_L    = 2048;
constexpr int F_IN     = 1024;
constexpr int D_OUT    = 128;
constexpr int N_DESC   = 80;
constexpr int K_PAD    = 104;
constexpr int N_CCH    = 16;
constexpr int ELL_CAP  = 64;
constexpr int S_SLICES = 32;
constexpr int ROWB     = N_PAD / 128;        // 158
constexpr int NWG_GEMM = 2 * ROWB * 8;       // 2528, divisible by 8
constexpr float SLOPE  = 0.01f;

// prep kernel (no big LDS) block ranges
constexpr int PR_FILL_END  = 2 * 625;                 // 1250
constexpr int PR_CONVT_END = PR_FILL_END + 2 * 1024;  // +2048
constexpr int PR_CAST_END  = PR_CONVT_END + 2 * (N_PAD / 2);  // +20224

typedef short bf16x8 __attribute__((ext_vector_type(8)));
typedef float f32x4  __attribute__((ext_vector_type(4)));
typedef float f32x2  __attribute__((ext_vector_type(2)));
typedef int   i32x4v __attribute__((ext_vector_type(4)));
typedef int   i32x8v __attribute__((ext_vector_type(8)));

__device__ __forceinline__ float leaky(float x) { return x > 0.f ? x : SLOPE * x; }
__device__ __forceinline__ ushort f2bf(float f) {
  uint32_t u = __float_as_uint(f);
  uint32_t r = (u + 0x7FFFu + ((u >> 16) & 1u)) >> 16;
  return (ushort)r;
}
__device__ __forceinline__ float bf2f(ushort u) { return __uint_as_float(((uint32_t)u) << 16); }

// ---- fp8 e4m3fn manual converters (exponent-remap, RNE) ----
__device__ __forceinline__ unsigned char f2fp8(float f) {
  f = fminf(fmaxf(f, -448.f), 448.f);
  uint32_t u = __float_as_uint(f * 0x1.0p-120f);
  uint32_t s = (u >> 24) & 0x80u;
  uint32_t m = u & 0x7FFFFFFFu;
  m = m + 0x7FFFFu + ((m >> 20) & 1u);
  return (unsigned char)(s | (m >> 20));
}
__device__ __forceinline__ float fp82f(uint32_t b) {
  uint32_t bits = ((b & 0x80u) << 24) | ((b & 0x7Fu) << 20);
  return __uint_as_float(bits) * 0x1.0p+120f;
}

// decode 4 packed fp8 (one u32) -> 4 floats; HW packed cvt when available
#if defined(__has_builtin)
#if __has_builtin(__builtin_amdgcn_cvt_pk_f32_fp8)
#define HAS_CVT_PK_FP8 1
#endif
#endif
__device__ __forceinline__ void dec4(uint32_t wv, float* d) {
#ifdef HAS_CVT_PK_FP8
  f32x2 lo = __builtin_amdgcn_cvt_pk_f32_fp8((int)wv, false);
  f32x2 hi = __builtin_amdgcn_cvt_pk_f32_fp8((int)wv, true);
  d[0] = lo[0]; d[1] = lo[1]; d[2] = hi[0]; d[3] = hi[1];
#else
#pragma unroll
  for (int j = 0; j < 4; ++j) d[j] = fp82f((wv >> (8 * j)) & 0xFFu);
#endif
}

__device__ __forceinline__ int lower_bound_i(const int* __restrict__ arr, int n, int val) {
  int lo = 0, hi = n;
  while (lo < hi) { int mid = (lo + hi) >> 1; if (arr[mid] < val) lo = mid + 1; else hi = mid; }
  return lo;
}

// ============ prep: fill_ell | convT(fp8 x32) | cast_pad(fp8) — small static LDS ============
__global__ __launch_bounds__(256) void prep_kernel(
    const int* __restrict__ e0, const int* __restrict__ e1,
    int* __restrict__ cnt, int* __restrict__ ell,
    const float* __restrict__ Wg0, const float* __restrict__ Wg1,
    unsigned char* __restrict__ wtf8,
    const float* __restrict__ x0, const float* __restrict__ x1,
    unsigned char* __restrict__ xf8) {
  __shared__ float tile[32][33];
  const int bid = blockIdx.x;
  const int t = threadIdx.x;

  if (bid < PR_FILL_END) {
    // ---- build ELL adjacency ----
    int z = bid >= 625;
    int i = (bid - z * 625) * 256 + t;
    const int* src = z ? e1 : e0;
    const int* dst = src + N_EDGES;
    int d = dst[i];
    int pos = atomicAdd(&cnt[z * N_NODES + d], 1);
    if (pos < ELL_CAP) ell[((size_t)z * N_NODES + d) * ELL_CAP + pos] = src[i];
  } else if (bid < PR_CONVT_END) {
    // ---- W [K=1024][N=1024] f32 -> Wt [N][K] fp8, PRE-SCALED x32 ----
    int cb = bid - PR_FILL_END;
    int z = cb >= 1024;
    int cb2 = cb - z * 1024;
    const float* W = z ? Wg1 : Wg0;
    const int k0 = (cb2 & 31) * 32, n0 = (cb2 >> 5) * 32;
    const int tc = t & 31, tr = t >> 5;
#pragma unroll
    for (int q = 0; q < 4; ++q) {
      int r = tr + q * 8;
      tile[r][tc] = W[(size_t)(k0 + r) * F_IN + n0 + tc];
    }
    __syncthreads();
    unsigned char* Wz = wtf8 + (size_t)z * F_IN * F_IN;
#pragma unroll
    for (int q = 0; q < 4; ++q) {
      int r = tr + q * 8;
      Wz[(size_t)(n0 + r) * F_IN + k0 + tc] = f2fp8(tile[tc][r] * 32.0f);
    }
  } else {
    // ---- x -> fp8 (pad rows zero); 8 elems/thread ----
    int cb = bid - PR_CONVT_END;
    int z = cb >= (N_PAD / 2);
    int cb2 = cb - z * (N_PAD / 2);
    const float* in = z ? x1 : x0;
    size_t i = ((size_t)cb2 * 256 + t) * 8;
    int row = (int)(i >> 10);
    uint2 o;
    if (row < N_NODES) {
      float4 v0 = *(const float4*)(in + i);
      float4 v1 = *(const float4*)(in + i + 4);
      o.x = (uint32_t)f2fp8(v0.x) | ((uint32_t)f2fp8(v0.y) << 8) |
            ((uint32_t)f2fp8(v0.z) << 16) | ((uint32_t)f2fp8(v0.w) << 24);
      o.y = (uint32_t)f2fp8(v1.x) | ((uint32_t)f2fp8(v1.y) << 8) |
            ((uint32_t)f2fp8(v1.z) << 16) | ((uint32_t)f2fp8(v1.w) << 24);
    } else {
      o.x = 0u; o.y = 0u;
    }
    *(uint2*)(xf8 + (size_t)z * N_PAD * F_IN + i) = o;
  }
}

// ============ conv1d(k=1) via MFMA — standalone, static 54 KB LDS, 1024 blocks ============
__global__ __launch_bounds__(256) void conv_mfma(
    const float* __restrict__ m0, const float* __restrict__ m1,
    const float* __restrict__ m2, const float* __restrict__ m3,
    const float* __restrict__ Wc0, const float* __restrict__ Wc1,
    const float* __restrict__ Wc2, const float* __restrict__ Wc3,
    float* __restrict__ pmax) {
  __shared__ ushort lA[128 * K_PAD];
  __shared__ ushort lB[128 * K_PAD];
  __shared__ float smax[4 * D_OUT];
  const int bid = blockIdx.x;
  const int t = threadIdx.x;
  const int ch = bid & 15, g = (bid >> 4) & 15, br = bid >> 8;
  const float* m = br == 0 ? m0 : br == 1 ? m1 : br == 2 ? m2 : m3;
  const float* W = br == 0 ? Wc0 : br == 1 ? Wc1 : br == 2 ? Wc2 : Wc3;
  const int lane = t & 63, w = t >> 6;

  for (int i = t; i < N_DESC * D_OUT; i += 256) {
    int k = i >> 7, col = i & 127;
    lB[col * K_PAD + k] = f2bf(W[i]);
  }
  for (int i = t; i < 128 * 16; i += 256) {
    int col = i >> 4, k = 80 + (i & 15);
    lB[col * K_PAD + k] = 0;
  }
  const float4* mg4 = (const float4*)(m + ((size_t)g * SEQ_L + (size_t)ch * 128) * N_DESC);
#pragma unroll
  for (int j = 0; j < 10; ++j) {
    int fi = t + j * 256;
    int row = fi / 20, off = fi - row * 20;
    float4 v = mg4[fi];
    ushort4 o;
    o.x = f2bf(v.x); o.y = f2bf(v.y); o.z = f2bf(v.z); o.w = f2bf(v.w);
    *(ushort4*)(lA + row * K_PAD + off * 4) = o;
  }
  if (t < 128) {
    ushort4 z4 = {0, 0, 0, 0};
    *(ushort4*)(lA + t * K_PAD + 80) = z4;
    *(ushort4*)(lA + t * K_PAD + 84) = z4;
    *(ushort4*)(lA + t * K_PAD + 88) = z4;
    *(ushort4*)(lA + t * K_PAD + 92) = z4;
  }
  __syncthreads();

  const int frow = lane & 15, fk = (lane >> 4) * 8;
  f32x4 acc[2][8] = {};
#pragma unroll
  for (int ks = 0; ks < 3; ++ks) {
    bf16x8 af[2], bfr[8];
#pragma unroll
    for (int mm = 0; mm < 2; ++mm)
      af[mm] = *(const bf16x8*)(lA + (w * 32 + mm * 16 + frow) * K_PAD + ks * 32 + fk);
#pragma unroll
    for (int n = 0; n < 8; ++n)
      bfr[n] = *(const bf16x8*)(lB + (n * 16 + frow) * K_PAD + ks * 32 + fk);
#pragma unroll
    for (int mm = 0; mm < 2; ++mm)
#pragma unroll
      for (int n = 0; n < 8; ++n)
        acc[mm][n] = __builtin_amdgcn_mfma_f32_16x16x32_bf16(af[mm], bfr[n], acc[mm][n], 0, 0, 0);
  }
  __syncthreads();

#pragma unroll
  for (int n = 0; n < 8; ++n) {
    float v = acc[0][n][0];
#pragma unroll
    for (int j = 1; j < 4; ++j) v = fmaxf(v, acc[0][n][j]);
#pragma unroll
    for (int j = 0; j < 4; ++j) v = fmaxf(v, acc[1][n][j]);
    v = fmaxf(v, __shfl_xor(v, 16, 64));
    v = fmaxf(v, __shfl_xor(v, 32, 64));
    if (lane < 16) smax[w * D_OUT + n * 16 + lane] = v;
  }
  __syncthreads();
  if (t < D_OUT) {
    float v = fmaxf(fmaxf(smax[t], smax[D_OUT + t]),
                    fmaxf(smax[2 * D_OUT + t], smax[3 * D_OUT + t]));
    pmax[(((size_t)br * N_GRAPHS + g) * N_CCH + ch) * D_OUT + t] = v;
  }
}

__device__ __forceinline__ i32x8v ld_frag8(const unsigned char* base, int s0, int s1) {
  i32x4v p0 = *(const i32x4v*)(base + (s0 << 4));
  i32x4v p1 = *(const i32x4v*)(base + (s1 << 4));
  i32x8v r;
  r[0] = p0[0]; r[1] = p0[1]; r[2] = p0[2]; r[3] = p0[3];
  r[4] = p1[0]; r[5] = p1[1]; r[6] = p1[2]; r[7] = p1[3];
  return r;
}

// ===== MX-fp8 MFMA GEMM: 128x128 tile, BK=128, mfma_scale 16x16x128, XOR-swizzled LDS =====
__global__ __launch_bounds__(256) void gemm_mx(const unsigned char* __restrict__ A,
                                               const unsigned char* __restrict__ Bt,
                                               const int* __restrict__ cnt,
                                               unsigned char* __restrict__ C) {
  const int bid = blockIdx.x;
  const int swz = (bid & 7) * (NWG_GEMM / 8) + (bid >> 3);
  const int br  = swz / (ROWB * 8);
  const int rem = swz - br * (ROWB * 8);
  const int rowb = rem >> 3, colb = rem & 7;

  const unsigned char* Az = A + (size_t)br * N_PAD * F_IN;
  const unsigned char* Bz = Bt + (size_t)br * F_IN * F_IN;
  unsigned char* Cz = C + (size_t)br * N_PAD * F_IN;
  const int* cz = cnt + br * N_NODES;

  __shared__ unsigned char lA[128 * 128];
  __shared__ unsigned char lB[128 * 128];
  const int t = threadIdx.x;
  const int lane = t & 63, w = t >> 6;
  const int wr = w >> 1, wc = w & 1;
  const int brow = rowb * 128, bcol = colb * 128;

  const int lr8 = lane >> 3;
  const int csw = ((lane & 7) ^ lr8) << 4;
  const unsigned char* gA[4]; const unsigned char* gB[4];
  int ldo[4];
#pragma unroll
  for (int g = 0; g < 4; ++g) {
    const int c = w * 4 + g;
    gA[g] = Az + (size_t)(brow + c * 8 + lr8) * F_IN + csw;
    gB[g] = Bz + (size_t)(bcol + c * 8 + lr8) * F_IN + csw;
    ldo[g] = c * 1024 + lane * 16;
  }

  f32x4 acc[4][4] = {};
  const int frow = lane & 15;
  const int kg = lane >> 4;
  const int xm = frow & 7;
  const int s0 = (2 * kg) ^ xm, s1 = (2 * kg + 1) ^ xm;

  for (int k0 = 0; k0 < F_IN; k0 += 128) {
#pragma unroll
    for (int g = 0; g < 4; ++g) {
      __builtin_amdgcn_global_load_lds((const __attribute__((address_space(1))) void*)(gA[g] + k0),
                                       (__attribute__((address_space(3))) void*)(lA + ldo[g]), 16, 0, 0);
      __builtin_amdgcn_global_load_lds((const __attribute__((address_space(1))) void*)(gB[g] + k0),
                                       (__attribute__((address_space(3))) void*)(lB + ldo[g]), 16, 0, 0);
    }
    __syncthreads();
    i32x8v af[4], bfv[4];
#pragma unroll
    for (int m = 0; m < 4; ++m)
      af[m] = ld_frag8(lA + (wr * 64 + m * 16 + frow) * 128, s0, s1);
#pragma unroll
    for (int n = 0; n < 4; ++n)
      bfv[n] = ld_frag8(lB + (wc * 64 + n * 16 + frow) * 128, s0, s1);
#pragma unroll
    for (int m = 0; m < 4; ++m)
#pragma unroll
      for (int n = 0; n < 4; ++n)
        acc[m][n] = __builtin_amdgcn_mfma_scale_f32_16x16x128_f8f6f4(
            af[m], bfv[n], acc[m][n], 0, 0,
            0, 0x7F7F7F7F,    // A scale = 2^0
            0, 0x7A7A7A7A);   // B scale = 2^-5
    __syncthreads();
  }

  float* ldv = (float*)lA;
  if (t < 128) {
    int row = brow + t;
    ldv[t] = (row < N_NODES) ? rsqrtf((float)(cz[row] + 1)) : 0.f;
  }
  __syncthreads();

#pragma unroll
  for (int m = 0; m < 4; ++m) {
    const int r0 = wr * 64 + m * 16 + (lane >> 4) * 4;
#pragma unroll
    for (int j = 0; j < 4; ++j) {
      const float dv = ldv[r0 + j];
      const int row = brow + r0 + j;
#pragma unroll
      for (int n = 0; n < 4; ++n) {
        const int col = bcol + wc * 64 + n * 16 + (lane & 15);
        Cz[(size_t)row * F_IN + col] = f2fp8(acc[m][n][j] * dv);
      }
    }
  }
}

// ===== GCN aggregate + mean-pool fused: uint4 row loads + HW packed fp8 decode =====
__global__ __launch_bounds__(256) void gcn_agg_pool(const unsigned char* __restrict__ hs,
                                                    const int* __restrict__ cnt,
                                                    const int* __restrict__ ell,
                                                    const int* __restrict__ bt0,
                                                    const int* __restrict__ bt1,
                                                    const float* __restrict__ b0,
                                                    const float* __restrict__ b1,
                                                    float* __restrict__ pool) {
  __shared__ float lp[4][1024];
  const int g = blockIdx.x;
  const int slice = blockIdx.y;
  const int z = blockIdx.z;
  const int sub = threadIdx.x >> 6;
  const int lane = threadIdx.x & 63;
  const int* batch = z ? bt1 : bt0;
  const unsigned char* hz = hs + (size_t)z * N_PAD * F_IN;
  const int* cz = cnt + z * N_NODES;
  const float* bias = z ? b1 : b0;

  int lo = lower_bound_i(batch, N_NODES, g);
  int hi = lower_bound_i(batch, N_NODES, g + 1);
  int per = (hi - lo + S_SLICES - 1) / S_SLICES;
  int a = lo + slice * per;
  int b = min(a + per, hi);
  if (a >= b) return;

  float bv[16];
#pragma unroll
  for (int k = 0; k < 4; ++k)
    *(float4*)(bv + 4 * k) = ((const float4*)bias)[lane * 4 + k];

  float pp[16] = {};
  for (int node = a + sub; node < b; node += 4) {
    const int deg = cz[node];
    const float din = rsqrtf((float)(deg + 1));
    uint4 hv = ((const uint4*)(hz + (size_t)node * F_IN))[lane];
    float acc[16];
    dec4(hv.x, acc); dec4(hv.y, acc + 4); dec4(hv.z, acc + 8); dec4(hv.w, acc + 12);
    const int* el = ell + ((size_t)z * N_NODES + node) * ELL_CAP;
    const int ne = min(deg, ELL_CAP);
    int e = 0;
    for (; e + 4 <= ne; e += 4) {
      int4 sx = *(const int4*)(el + e);
      uint4 v0 = ((const uint4*)(hz + (size_t)sx.x * F_IN))[lane];
      uint4 v1 = ((const uint4*)(hz + (size_t)sx.y * F_IN))[lane];
      uint4 v2 = ((const uint4*)(hz + (size_t)sx.z * F_IN))[lane];
      uint4 v3 = ((const uint4*)(hz + (size_t)sx.w * F_IN))[lane];
      float d0[16], d1[16], d2[16], d3[16];
      dec4(v0.x, d0); dec4(v0.y, d0 + 4); dec4(v0.z, d0 + 8); dec4(v0.w, d0 + 12);
      dec4(v1.x, d1); dec4(v1.y, d1 + 4); dec4(v1.z, d1 + 8); dec4(v1.w, d1 + 12);
      dec4(v2.x, d2); dec4(v2.y, d2 + 4); dec4(v2.z, d2 + 8); dec4(v2.w, d2 + 12);
      dec4(v3.x, d3); dec4(v3.y, d3 + 4); dec4(v3.z, d3 + 8); dec4(v3.w, d3 + 12);
#pragma unroll
      for (int j = 0; j < 16; ++j)
        acc[j] += (d0[j] + d1[j]) + (d2[j] + d3[j]);
    }
    for (; e < ne; ++e) {
      uint4 v0 = ((const uint4*)(hz + (size_t)el[e] * F_IN))[lane];
      float d0[16];
      dec4(v0.x, d0); dec4(v0.y, d0 + 4); dec4(v0.z, d0 + 8); dec4(v0.w, d0 + 12);
#pragma unroll
      for (int j = 0; j < 16; ++j) acc[j] += d0[j];
    }
#pragma unroll
    for (int j = 0; j < 16; ++j) pp[j] += leaky(din * acc[j] + bv[j]);
  }

#pragma unroll
  for (int k = 0; k < 4; ++k)
    *(float4*)(&lp[sub][lane * 16 + 4 * k]) = *(const float4*)(pp + 4 * k);
  __syncthreads();
  float* pg = pool + ((size_t)z * N_GRAPHS + g) * F_IN;
#pragma unroll
  for (int q = 0; q < 4; ++q) {
    int i = threadIdx.x + q * 256;
    float s = (lp[0][i] + lp[1][i]) + (lp[2][i] + lp[3][i]);
    atomicAdd(&pg[i], s);
  }
}

// ================= T1: conv_reduce | fc, fused =================
__global__ __launch_bounds__(256) void tail1(const float* __restrict__ pmax,
                                             const float* __restrict__ cb0, const float* __restrict__ cb1,
                                             const float* __restrict__ cb2, const float* __restrict__ cb3,
                                             const float* __restrict__ pool,
                                             const int* __restrict__ bt0, const int* __restrict__ bt1,
                                             const float* __restrict__ W0, const float* __restrict__ W1,
                                             const float* __restrict__ fb0, const float* __restrict__ fb1,
                                             float* __restrict__ combined) {
  __shared__ float p[2][F_IN];
  const int bid = blockIdx.x;
  const int t = threadIdx.x;
  if (bid < 32) {
    int i = bid * 256 + t;
    int br = i >> 11;
    int g = (i >> 7) & 15;
    int d = i & 127;
    const float* pm = pmax + ((size_t)(br * N_GRAPHS + g) * N_CCH) * D_OUT + d;
    float best = -3.4e38f;
#pragma unroll
    for (int ch = 0; ch < N_CCH; ++ch) best = fmaxf(best, pm[ch * D_OUT]);
    const float* bias = br == 0 ? cb0 : br == 1 ? cb1 : br == 2 ? cb2 : cb3;
    combined[g * (6 * D_OUT) + 2 * D_OUT + br * D_OUT + d] = leaky(best + bias[d]);
  } else {
    int idx = (bid - 32) * 2 + (t >> 7);
    int z = idx >> 4, g = idx & 15;
    int tt = t & 127, sub = t >> 7;
    const int* batch = z ? bt1 : bt0;
    const float* W = z ? W1 : W0;
    const float* bias = z ? fb1 : fb0;
    int lo = lower_bound_i(batch, N_NODES, g);
    int hi = lower_bound_i(batch, N_NODES, g + 1);
    float inv = 1.0f / (float)max(hi - lo, 1);
    const float* pg = pool + ((size_t)z * N_GRAPHS + g) * F_IN;
    for (int k = tt; k < F_IN; k += 128) p[sub][k] = pg[k] * inv;
    __syncthreads();
    float acc = 0.f;
    for (int k = 0; k < F_IN; ++k) acc = fmaf(p[sub][k], W[k * D_OUT + tt], acc);
    combined[g * (6 * D_OUT) + z * D_OUT + tt] = leaky(acc + bias[tt]);
  }
}

// ================= final linear =================
__global__ __launch_bounds__(256) void final_kernel(const float* __restrict__ combined,
                                                    const float* __restrict__ Wf,
                                                    const float* __restrict__ bf,
                                                    float* __restrict__ out) {
  const int g = blockIdx.x;
  const int t = threadIdx.x;
  float acc = 0.f;
  for (int k = t; k < 6 * D_OUT; k += 256) acc = fmaf(combined[g * 6 * D_OUT + k], Wf[k], acc);
  __shared__ float red[256];
  red[t] = acc;
  __syncthreads();
  for (int s = 128; s > 0; s >>= 1) {
    if (t < s) red[t] += red[t + s];
    __syncthreads();
  }
  if (t == 0) out[g] = red[0] + bf[0];
}

extern "C" void kernel_launch(void* const* d_in, const int* in_sizes, int n_in,
                              void* d_out, int out_size, void* d_ws, size_t ws_size,
                              hipStream_t stream) {
  const float* p1x  = (const float*)d_in[0];
  const int*   e1   = (const int*)d_in[1];
  const int*   bt1  = (const int*)d_in[2];
  const float* p2x  = (const float*)d_in[3];
  const int*   e2   = (const int*)d_in[4];
  const int*   bt2  = (const int*)d_in[5];
  const float* m1s  = (const float*)d_in[6];
  const float* m1f  = (const float*)d_in[7];
  const float* m2s  = (const float*)d_in[8];
  const float* m2f  = (const float*)d_in[9];
  const float* Wg1  = (const float*)d_in[10];
  const float* bg1  = (const float*)d_in[11];
  const float* Wfc1 = (const float*)d_in[12];
  const float* bfc1 = (const float*)d_in[13];
  const float* Wg2  = (const float*)d_in[14];
  const float* bg2  = (const float*)d_in[15];
  const float* Wfc2 = (const float*)d_in[16];
  const float* bfc2 = (const float*)d_in[17];
  const float* Wm1s = (const float*)d_in[18];
  const float* bm1s = (const float*)d_in[19];
  const float* Wm1f = (const float*)d_in[20];
  const float* bm1f = (const float*)d_in[21];
  const float* Wm2s = (const float*)d_in[22];
  const float* bm2s = (const float*)d_in[23];
  const float* Wm2f = (const float*)d_in[24];
  const float* bm2f = (const float*)d_in[25];
  const float* Wfin = (const float*)d_in[26];
  const float* bfin = (const float*)d_in[27];
  float* out = (float*)d_out;

  char* base = (char*)d_ws;
  size_t off = 0;
  auto alloc = [&](size_t bytes) -> void* {
    void* p = base + off;
    off = (off + bytes + 255) & ~(size_t)255;
    return p;
  };
  unsigned char* xf8  = (unsigned char*)alloc((size_t)2 * N_PAD * F_IN);
  unsigned char* wtf8 = (unsigned char*)alloc((size_t)2 * F_IN * F_IN);
  unsigned char* h    = (unsigned char*)alloc((size_t)2 * N_PAD * F_IN);
  size_t zoff0 = off;
  int*    cnt    = (int*)alloc((size_t)2 * N_NODES * 4);
  float*  pool   = (float*)alloc((size_t)2 * N_GRAPHS * F_IN * 4);
  size_t zbytes = off - zoff0;
  int*    ell    = (int*)alloc((size_t)2 * N_NODES * ELL_CAP * 4);
  float*  combined = (float*)alloc((size_t)N_GRAPHS * 6 * D_OUT * 4);
  float*  pmax   = (float*)alloc((size_t)4 * N_GRAPHS * N_CCH * D_OUT * 4);
  (void)ws_size; (void)in_sizes; (void)n_in; (void)out_size;

  hipMemsetAsync((char*)base + zoff0, 0, zbytes, stream);

  // split by LDS need: prep (4 KB static -> full occupancy) + conv_mfma (54 KB static)
  prep_kernel<<<PR_CAST_END, 256, 0, stream>>>(e1, e2, cnt, ell, Wg1, Wg2, wtf8, p1x, p2x, xf8);
  conv_mfma<<<1024, 256, 0, stream>>>(m1s, m1f, m2s, m2f, Wm1s, Wm1f, Wm2s, Wm2f, pmax);

  gemm_mx<<<NWG_GEMM, 256, 0, stream>>>(xf8, wtf8, cnt, h);

  gcn_agg_pool<<<dim3(N_GRAPHS, S_SLICES, 2), 256, 0, stream>>>(h, cnt, ell, bt1, bt2, bg1, bg2, pool);

  tail1<<<48, 256, 0, stream>>>(pmax, bm1s, bm1f, bm2s, bm2f,
                                pool, bt1, bt2, Wfc1, Wfc2, bfc1, bfc2, combined);

  final_kernel<<<N_GRAPHS, 256, 0, stream>>>(combined, Wfin, bfin, out);
}